// Round 2
// baseline (25090.343 us; speedup 1.0000x reference)
//
#include <hip/hip_runtime.h>
#include <math.h>

// EncoderDecoder LSTM seq2seq, f32 throughout (argmax feedback requires
// reference-matching precision; no fp32 MFMA on CDNA4 anyway).
//
// B=32, S=128, I=512, H=1024, V=32000, T=64.
// Encoder: 128 steps x 2 layers. Decoder: 64 steps x (2 cells + logits+argmax).
// All sequential -> one kernel per step-layer, captured in the graph.

#define BB   32
#define SEQ  128
#define HID  1024
#define NV   32000
#define TDEC 64

__device__ __forceinline__ float sgm(float x) { return 1.0f / (1.0f + expf(-x)); }

// ---------------------------------------------------------------------------
// Fused LSTM cell: gates = x @ Wih^T + h @ Whh^T + b ; pointwise update.
// grid = 256 blocks (4 hidden cols j each), block = 512 thr = ks(8) x jj(2) x b(32).
// Each thread: 2 j x 4 gates partial dots over K/8 slice; LDS reduce; 128
// finalizer threads do the pointwise update.
// Activations (x row ++ h row) staged in LDS per 32-wide K chunk with XOR
// swizzle (row stride 128B would be a 32-way bank conflict on ds_read_b128).
// ---------------------------------------------------------------------------
template <int XK>
__global__ void __launch_bounds__(512) lstm_cell(
    const float* __restrict__ xdir,            // [BB][XK] or nullptr
    const float* __restrict__ emb,             // [V][XK] or nullptr
    const int*   __restrict__ idx, int idx_stride, int idx_off,
    const float* __restrict__ Wih,             // [4H][XK]
    const float* __restrict__ Whh,             // [4H][H]
    const float* __restrict__ bias,            // [4H]
    const float* __restrict__ h_in,            // [BB][H]
    float*       __restrict__ h_out,           // [BB][H]
    float*       __restrict__ c)               // [BB][H] in/out
{
    constexpr int KT  = XK + HID;   // total K
    constexpr int KQ  = KT / 8;     // per-ks K slice
    constexpr int NCH = KQ / 32;    // 32-wide chunks per slice

    __shared__ float act[8 * 32 * 32];            // [ks][b][kk], swizzled
    __shared__ float part[8][2][2][32][4];        // [ks][jj][p][b][g]

    const int tid = threadIdx.x;
    const int b   = tid & 31;
    const int jj  = (tid >> 5) & 1;
    const int ks  = tid >> 6;
    const int j0  = blockIdx.x * 4;
    const int jA  = j0 + jj * 2;

    // loader coords: thread loads 16 consecutive floats of row b in its ks slice
    const int lh = jj;  // which 16-half of the 32-chunk
    const float* xrow;
    if (emb) xrow = emb + (size_t)idx[b * idx_stride + idx_off] * XK;
    else     xrow = xdir + (size_t)b * XK;
    const float* hrow = h_in + (size_t)b * HID;

    float acc[2][4];
#pragma unroll
    for (int p = 0; p < 2; ++p)
#pragma unroll
        for (int g = 0; g < 4; ++g) acc[p][g] = 0.0f;

    for (int ci = 0; ci < NCH; ++ci) {
        __syncthreads();
        {
            const int lk0 = ks * KQ + ci * 32 + lh * 16;  // 16-aligned; XK is 32-aligned
            const float* src = (lk0 < XK) ? (xrow + lk0) : (hrow + (lk0 - XK));
            const int base = (ks * 32 + b) * 32 + lh * 16;
            const int sw   = (b & 7) << 2;
            float4 u0 = *reinterpret_cast<const float4*>(src + 0);
            float4 u1 = *reinterpret_cast<const float4*>(src + 4);
            float4 u2 = *reinterpret_cast<const float4*>(src + 8);
            float4 u3 = *reinterpret_cast<const float4*>(src + 12);
            *reinterpret_cast<float4*>(&act[(base + 0)  ^ sw]) = u0;
            *reinterpret_cast<float4*>(&act[(base + 4)  ^ sw]) = u1;
            *reinterpret_cast<float4*>(&act[(base + 8)  ^ sw]) = u2;
            *reinterpret_cast<float4*>(&act[(base + 12) ^ sw]) = u3;
        }
        __syncthreads();

        const int k0 = ks * KQ + ci * 32;  // chunk is entirely on one side of XK
        const float* wb; int wofs, wld;
        if (k0 < XK) { wb = Wih; wofs = k0;      wld = XK;  }
        else         { wb = Whh; wofs = k0 - XK; wld = HID; }

        const float* wp[2][4];
#pragma unroll
        for (int p = 0; p < 2; ++p)
#pragma unroll
            for (int g = 0; g < 4; ++g)
                wp[p][g] = wb + (size_t)(jA + p + g * HID) * wld + wofs;

        const int abase = (ks * 32 + b) * 32;
        const int sw    = (b & 7) << 2;
#pragma unroll
        for (int kk = 0; kk < 32; kk += 4) {
            const float4 a = *reinterpret_cast<const float4*>(&act[(abase + kk) ^ sw]);
#pragma unroll
            for (int p = 0; p < 2; ++p)
#pragma unroll
                for (int g = 0; g < 4; ++g) {
                    const float4 w = *reinterpret_cast<const float4*>(wp[p][g] + kk);
                    acc[p][g] += a.x * w.x + a.y * w.y + a.z * w.z + a.w * w.w;
                }
        }
    }

#pragma unroll
    for (int p = 0; p < 2; ++p)
#pragma unroll
        for (int g = 0; g < 4; ++g) part[ks][jj][p][b][g] = acc[p][g];
    __syncthreads();

    if (tid < 128) {
        const int fb  = tid & 31;
        const int fjj = (tid >> 5) & 1;
        const int fp  = (tid >> 6) & 1;
        const int j   = j0 + fjj * 2 + fp;
        float gi = 0.f, gf = 0.f, gg = 0.f, go = 0.f;
#pragma unroll
        for (int s = 0; s < 8; ++s) {
            gi += part[s][fjj][fp][fb][0];
            gf += part[s][fjj][fp][fb][1];
            gg += part[s][fjj][fp][fb][2];
            go += part[s][fjj][fp][fb][3];
        }
        gi += bias[j];
        gf += bias[j + HID];
        gg += bias[j + 2 * HID];
        go += bias[j + 3 * HID];
        const float cprev = c[fb * HID + j];
        const float cn = sgm(gf) * cprev + sgm(gi) * tanhf(gg);
        const float hn = sgm(go) * tanhf(cn);
        c[fb * HID + j]     = cn;
        h_out[fb * HID + j] = hn;
    }
}

// ---------------------------------------------------------------------------
// Logits: out[b][t][v] = h1[b] . pred_W[v] + pred_b[v]; per-block argmax partials.
// grid = 500 blocks (64 v each), block = 256 thr = vv(8) x b(32); 8 v/thread.
// ---------------------------------------------------------------------------
__global__ void __launch_bounds__(256) logits_kernel(
    const float* __restrict__ h1,    // [BB][H]
    const float* __restrict__ W,     // [V][H]
    const float* __restrict__ bias,  // [V]
    float*       __restrict__ out,   // [BB][TDEC][1][V]
    int t,
    float*       __restrict__ pval,  // [500][BB]
    int*         __restrict__ pidx)  // [500][BB]
{
    __shared__ float act[32 * 64];   // [b][kk], swizzled
    __shared__ float rv[8][32];
    __shared__ int   ri[8][32];

    const int tid = threadIdx.x;
    const int b   = tid & 31;
    const int vv  = tid >> 5;
    const int v0  = blockIdx.x * 64 + vv * 8;

    float acc[8];
#pragma unroll
    for (int i = 0; i < 8; ++i) acc[i] = 0.0f;

    const int lb = tid >> 3;
    const int ls = tid & 7;

    for (int ci = 0; ci < HID / 64; ++ci) {
        __syncthreads();
        {
            const float* src = h1 + (size_t)lb * HID + ci * 64 + ls * 8;
            const int base = lb * 64 + ls * 8;
            const int sw   = (lb & 7) << 2;
            float4 u0 = *reinterpret_cast<const float4*>(src);
            float4 u1 = *reinterpret_cast<const float4*>(src + 4);
            *reinterpret_cast<float4*>(&act[(base)     ^ sw]) = u0;
            *reinterpret_cast<float4*>(&act[(base + 4) ^ sw]) = u1;
        }
        __syncthreads();

        const float* wr[8];
#pragma unroll
        for (int i = 0; i < 8; ++i) wr[i] = W + (size_t)(v0 + i) * HID + ci * 64;

        const int abase = b * 64;
        const int sw    = (b & 7) << 2;
#pragma unroll
        for (int kk = 0; kk < 64; kk += 4) {
            const float4 a = *reinterpret_cast<const float4*>(&act[(abase + kk) ^ sw]);
#pragma unroll
            for (int i = 0; i < 8; ++i) {
                const float4 w = *reinterpret_cast<const float4*>(wr[i] + kk);
                acc[i] += a.x * w.x + a.y * w.y + a.z * w.z + a.w * w.w;
            }
        }
    }

    float res[8];
    float bestv = -3.402823e38f;
    int   besti = 0;
#pragma unroll
    for (int i = 0; i < 8; ++i) {
        const float L = acc[i] + bias[v0 + i];
        res[i] = L;
        if (L > bestv) { bestv = L; besti = v0 + i; }  // ascending i -> first max kept
    }
    const size_t obase = ((size_t)b * TDEC + t) * (size_t)NV + v0;
    *reinterpret_cast<float4*>(&out[obase])     = make_float4(res[0], res[1], res[2], res[3]);
    *reinterpret_cast<float4*>(&out[obase + 4]) = make_float4(res[4], res[5], res[6], res[7]);

    rv[vv][b] = bestv;
    ri[vv][b] = besti;
    __syncthreads();
    if (vv == 0) {
        float bv = rv[0][b];
        int   bi = ri[0][b];
#pragma unroll
        for (int i = 1; i < 8; ++i) {
            const float v = rv[i][b];
            const int  ix = ri[i][b];
            if (v > bv || (v == bv && ix < bi)) { bv = v; bi = ix; }
        }
        pval[(size_t)blockIdx.x * BB + b] = bv;
        pidx[(size_t)blockIdx.x * BB + b] = bi;
    }
}

// Final argmax reduce over the 500 block partials; first-index tie-break
// (matches jnp.argmax). One block per batch element.
__global__ void __launch_bounds__(256) argmax_final(
    const float* __restrict__ pval, const int* __restrict__ pidx,
    int nblk, int* __restrict__ tok)
{
    __shared__ float sv[256];
    __shared__ int   si[256];
    const int b   = blockIdx.x;
    const int tid = threadIdx.x;
    float bv = -3.402823e38f;
    int   bi = 0x7fffffff;
    for (int p = tid; p < nblk; p += 256) {
        const float v = pval[(size_t)p * BB + b];
        const int  ix = pidx[(size_t)p * BB + b];
        if (v > bv || (v == bv && ix < bi)) { bv = v; bi = ix; }
    }
    sv[tid] = bv; si[tid] = bi;
    __syncthreads();
    for (int s = 128; s > 0; s >>= 1) {
        if (tid < s) {
            const float v = sv[tid + s];
            const int  ix = si[tid + s];
            if (v > sv[tid] || (v == sv[tid] && ix < si[tid])) { sv[tid] = v; si[tid] = ix; }
        }
        __syncthreads();
    }
    if (tid == 0) tok[b] = si[0];
}

__global__ void __launch_bounds__(256) init_state(
    float* h0, float* c0, float* h1, float* c1, int* tok)
{
    const int i = blockIdx.x * 256 + threadIdx.x;
    if (i < BB * HID) { h0[i] = 0.f; c0[i] = 0.f; h1[i] = 0.f; c1[i] = 0.f; }
    if (i < BB) tok[i] = 1;  // BOS
}

// ---------------------------------------------------------------------------
extern "C" void kernel_launch(void* const* d_in, const int* in_sizes, int n_in,
                              void* d_out, int out_size, void* d_ws, size_t ws_size,
                              hipStream_t stream)
{
    const int*   x       = (const int*)  d_in[0];
    const float* enc_emb = (const float*)d_in[1];
    const float* dec_emb = (const float*)d_in[2];
    const float* eWih0   = (const float*)d_in[3];
    const float* eWhh0   = (const float*)d_in[4];
    const float* eb0     = (const float*)d_in[5];
    const float* eWih1   = (const float*)d_in[6];
    const float* eWhh1   = (const float*)d_in[7];
    const float* eb1     = (const float*)d_in[8];
    const float* dWih0   = (const float*)d_in[9];
    const float* dWhh0   = (const float*)d_in[10];
    const float* db0     = (const float*)d_in[11];
    const float* dWih1   = (const float*)d_in[12];
    const float* dWhh1   = (const float*)d_in[13];
    const float* db1     = (const float*)d_in[14];
    const float* pW      = (const float*)d_in[15];
    const float* pb      = (const float*)d_in[16];
    float* out = (float*)d_out;

    // workspace layout (floats): h0 ping-pong, c0, h1 ping-pong, c1, tok, argmax partials
    float* w = (float*)d_ws;
    float* h0buf[2] = { w, w + 32768 };
    float* c0       = w + 65536;
    float* h1buf[2] = { w + 98304, w + 131072 };
    float* c1       = w + 163840;
    int*   tok      = (int*)(w + 196608);
    float* pval     = w + 196608 + 64;
    int*   pidx     = (int*)(w + 196608 + 64 + 16000);

    init_state<<<dim3(128), dim3(256), 0, stream>>>(h0buf[0], c0, h1buf[0], c1, tok);

    int cur0 = 0, cur1 = 0;

    // ---- encoder: 128 steps x 2 layers ----
    for (int t = 0; t < SEQ; ++t) {
        lstm_cell<512><<<dim3(256), dim3(512), 0, stream>>>(
            nullptr, enc_emb, x, SEQ, t,
            eWih0, eWhh0, eb0, h0buf[cur0], h0buf[cur0 ^ 1], c0);
        cur0 ^= 1;
        lstm_cell<1024><<<dim3(256), dim3(512), 0, stream>>>(
            h0buf[cur0], nullptr, nullptr, 0, 0,
            eWih1, eWhh1, eb1, h1buf[cur1], h1buf[cur1 ^ 1], c1);
        cur1 ^= 1;
    }

    // ---- decoder: 64 greedy steps (state continues from encoder) ----
    for (int t = 0; t < TDEC; ++t) {
        lstm_cell<1024><<<dim3(256), dim3(512), 0, stream>>>(
            nullptr, dec_emb, tok, 1, 0,
            dWih0, dWhh0, db0, h0buf[cur0], h0buf[cur0 ^ 1], c0);
        cur0 ^= 1;
        lstm_cell<1024><<<dim3(256), dim3(512), 0, stream>>>(
            h0buf[cur0], nullptr, nullptr, 0, 0,
            dWih1, dWhh1, db1, h1buf[cur1], h1buf[cur1 ^ 1], c1);
        cur1 ^= 1;
        logits_kernel<<<dim3(500), dim3(256), 0, stream>>>(
            h1buf[cur1], pW, pb, out, t, pval, pidx);
        argmax_final<<<dim3(32), dim3(256), 0, stream>>>(pval, pidx, 500, tok);
    }
}

// Round 3
// 16797.055 us; speedup vs baseline: 1.4937x; 1.4937x over previous
//
#include <hip/hip_runtime.h>
#include <math.h>

// EncoderDecoder LSTM seq2seq, f32 throughout (argmax feedback requires
// reference-matching precision; no fp32 MFMA on CDNA4).
//
// v2: both GEMMs restructured so global loads are fully coalesced (16B/lane)
// into LDS tiles; compute reads LDS with broadcast (W) or XOR-swizzled
// spread (activations). Round-2's 49us/dispatch came from broadcast VMEM
// weight loads (32B useful data per instruction) + 1 block/CU barrier drains.

#define BB   32
#define SEQ  128
#define HID  1024
#define NV   32000
#define TDEC 64

__device__ __forceinline__ float sgm(float x) { return 1.0f / (1.0f + expf(-x)); }

// ---------------------------------------------------------------------------
// Fused LSTM cell. grid = 512 blocks (2 j-cols each => 8 W rows), block = 512.
// Thread map: b = tid&31, ks = (tid>>5)&3 (K split), ng = tid>>7 (row pair).
// Per 256-wide K chunk: stage W rows (8x256, coalesced) + act rows (32x256,
// XOR-swizzled via pre-swizzled global source) into LDS; each thread
// accumulates 2 rows x 64 k. LDS reduce over ks, then 64 finalizer threads
// apply the LSTM pointwise update for j0..j0+1 (all 4 gates resident).
// ---------------------------------------------------------------------------
template <int XK>
__global__ void __launch_bounds__(512) lstm_cell(
    const float* __restrict__ xdir,            // [BB][XK] or nullptr
    const float* __restrict__ emb,             // [V][XK] or nullptr
    const int*   __restrict__ idx, int idx_stride, int idx_off,
    const float* __restrict__ Wih,             // [4H][XK]
    const float* __restrict__ Whh,             // [4H][H]
    const float* __restrict__ bias,            // [4H]
    const float* __restrict__ h_in,            // [BB][H]
    float*       __restrict__ h_out,           // [BB][H]
    float*       __restrict__ c_st)            // [BB][H] in/out
{
    constexpr int KT  = XK + HID;
    constexpr int NCH = KT / 256;

    __shared__ float Wch[8 * 256];    // 8KB, linear (reads are broadcast)
    __shared__ float Ach[32 * 256];   // 32KB, kk XOR-swizzled per row
    __shared__ float part[4 * 8 * 32];

    const int tid = threadIdx.x;
    const int b   = tid & 31;
    const int ks  = (tid >> 5) & 3;
    const int ng  = tid >> 7;             // 0..3 -> rows ng*2, ng*2+1
    const int j0  = blockIdx.x * 2;

    // --- staging coords ---
    const int wr = tid >> 6;              // W row 0..7 (wave w stages row w)
    const int wl = tid & 63;              // float4 slot within 1KB row
    const int wjl = wr >> 2, wg = wr & 3; // row r: jl = r>>2, g = r&3
    const int wn  = j0 + wjl + wg * HID;  // global W row

    const int ar  = tid >> 4;             // act row 0..31
    const int al  = tid & 15;             // slot base (4 slots: al+16*i)
    const int asw = (ar & 7) << 2;        // source-side swizzle (floats)

    const float* arow;
    if (emb) arow = emb + (size_t)idx[ar * idx_stride + idx_off] * XK;
    else     arow = xdir + (size_t)ar * XK;
    const float* hrow = h_in + (size_t)ar * HID;

    const int bsw = (b & 7) << 2;         // read-side swizzle
    const int r0 = ng * 2, r1 = ng * 2 + 1;
    float acc0 = 0.0f, acc1 = 0.0f;

    for (int ch = 0; ch < NCH; ++ch) {
        const int k0 = ch * 256;          // chunk never straddles the XK boundary

        // issue global loads BEFORE the barrier (latency hides under the
        // other resident block + tail of previous chunk's compute)
        const float* wsrc = (k0 < XK) ? (Wih + (size_t)wn * XK + k0)
                                      : (Whh + (size_t)wn * HID + (k0 - XK));
        const float4 wv = *reinterpret_cast<const float4*>(wsrc + wl * 4);

        const float* asrc = (k0 < XK) ? (arow + k0) : (hrow + (k0 - XK));
        const float4 a0 = *reinterpret_cast<const float4*>(asrc + (((al     ) * 4) ^ asw));
        const float4 a1 = *reinterpret_cast<const float4*>(asrc + (((al + 16) * 4) ^ asw));
        const float4 a2 = *reinterpret_cast<const float4*>(asrc + (((al + 32) * 4) ^ asw));
        const float4 a3 = *reinterpret_cast<const float4*>(asrc + (((al + 48) * 4) ^ asw));

        __syncthreads();  // previous chunk's readers done
        *reinterpret_cast<float4*>(&Wch[wr * 256 + wl * 4])        = wv;
        *reinterpret_cast<float4*>(&Ach[ar * 256 + (al     ) * 4]) = a0;
        *reinterpret_cast<float4*>(&Ach[ar * 256 + (al + 16) * 4]) = a1;
        *reinterpret_cast<float4*>(&Ach[ar * 256 + (al + 32) * 4]) = a2;
        *reinterpret_cast<float4*>(&Ach[ar * 256 + (al + 48) * 4]) = a3;
        __syncthreads();

        const int kb = ks * 64;
#pragma unroll
        for (int kk = 0; kk < 64; kk += 4) {
            const float4 a  = *reinterpret_cast<const float4*>(&Ach[b * 256 + ((kb + kk) ^ bsw)]);
            const float4 w0 = *reinterpret_cast<const float4*>(&Wch[r0 * 256 + kb + kk]);
            const float4 w1 = *reinterpret_cast<const float4*>(&Wch[r1 * 256 + kb + kk]);
            acc0 += a.x * w0.x + a.y * w0.y + a.z * w0.z + a.w * w0.w;
            acc1 += a.x * w1.x + a.y * w1.y + a.z * w1.z + a.w * w1.w;
        }
    }

    part[(ks * 8 + r0) * 32 + b] = acc0;
    part[(ks * 8 + r1) * 32 + b] = acc1;
    __syncthreads();

    if (tid < 64) {
        const int fb = tid & 31, jl = tid >> 5;
        const int j  = j0 + jl;
        float g4[4];
#pragma unroll
        for (int g = 0; g < 4; ++g) {
            const int r = jl * 4 + g;
            const float s = part[(0 * 8 + r) * 32 + fb] + part[(1 * 8 + r) * 32 + fb]
                          + part[(2 * 8 + r) * 32 + fb] + part[(3 * 8 + r) * 32 + fb];
            g4[g] = s + bias[j + g * HID];
        }
        const float cp = c_st[fb * HID + j];
        const float cn = sgm(g4[1]) * cp + sgm(g4[0]) * tanhf(g4[2]);
        const float hn = sgm(g4[3]) * tanhf(cn);
        c_st[fb * HID + j]  = cn;
        h_out[fb * HID + j] = hn;
    }
}

// ---------------------------------------------------------------------------
// Logits + per-block argmax partials. grid = 500 (64 v each), block = 512.
// Thread map: b = tid&31, vs = tid>>5 (16 groups of 4 v). Per 128-wide K
// chunk: stage W (64x128) + act (32x128, swizzled) to LDS coalesced; each
// thread accumulates 4 v rows over the whole chunk (no split-K).
// ---------------------------------------------------------------------------
__global__ void __launch_bounds__(512) logits_kernel(
    const float* __restrict__ h1,    // [BB][H]
    const float* __restrict__ W,     // [V][H]
    const float* __restrict__ bias,  // [V]
    float*       __restrict__ out,   // [BB][TDEC][1][V]
    int t,
    float*       __restrict__ pval,  // [500][BB]
    int*         __restrict__ pidx)  // [500][BB]
{
    __shared__ float Wch[64 * 128];  // 32KB
    __shared__ float Ach[32 * 128];  // 16KB
    __shared__ float rv[16 * 32];
    __shared__ int   ri[16 * 32];

    const int tid = threadIdx.x;
    const int b   = tid & 31;
    const int vs  = tid >> 5;        // 0..15
    const int v0  = blockIdx.x * 64;
    const int bsw = (b & 7) << 2;

    float acc[4] = {0.f, 0.f, 0.f, 0.f};

    for (int ch = 0; ch < 8; ++ch) {
        const int k0 = ch * 128;

        // stage W: 2048 float4, 4 per thread (slot s = tid + 512*i)
        float4 wv[4]; int wro[4], wco[4];
#pragma unroll
        for (int i = 0; i < 4; ++i) {
            const int s = tid + 512 * i;
            wro[i] = s >> 5; wco[i] = (s & 31) * 4;
            wv[i] = *reinterpret_cast<const float4*>(W + (size_t)(v0 + wro[i]) * HID + k0 + wco[i]);
        }
        // stage act: 1024 float4, 2 per thread, source pre-swizzled
        float4 av[2]; int aro[2], aco[2];
#pragma unroll
        for (int i = 0; i < 2; ++i) {
            const int s = tid + 512 * i;
            aro[i] = s >> 5; aco[i] = (s & 31) * 4;
            const int sw = (aro[i] & 7) << 2;
            av[i] = *reinterpret_cast<const float4*>(h1 + (size_t)aro[i] * HID + k0 + (aco[i] ^ sw));
        }

        __syncthreads();
#pragma unroll
        for (int i = 0; i < 4; ++i)
            *reinterpret_cast<float4*>(&Wch[wro[i] * 128 + wco[i]]) = wv[i];
#pragma unroll
        for (int i = 0; i < 2; ++i)
            *reinterpret_cast<float4*>(&Ach[aro[i] * 128 + aco[i]]) = av[i];
        __syncthreads();

#pragma unroll
        for (int kk = 0; kk < 128; kk += 4) {
            const float4 a = *reinterpret_cast<const float4*>(&Ach[b * 128 + (kk ^ bsw)]);
#pragma unroll
            for (int i = 0; i < 4; ++i) {
                const float4 w = *reinterpret_cast<const float4*>(&Wch[(vs * 4 + i) * 128 + kk]);
                acc[i] += a.x * w.x + a.y * w.y + a.z * w.z + a.w * w.w;
            }
        }
    }

    // bias + output + local argmax (ascending v => first-max tie-break)
    const int vbase = v0 + vs * 4;
    float res[4];
    float bestv = -3.402823e38f;
    int   besti = 0;
#pragma unroll
    for (int i = 0; i < 4; ++i) {
        res[i] = acc[i] + bias[vbase + i];
        if (res[i] > bestv) { bestv = res[i]; besti = vbase + i; }
    }
    const size_t obase = ((size_t)b * TDEC + t) * (size_t)NV + vbase;
    *reinterpret_cast<float4*>(&out[obase]) = make_float4(res[0], res[1], res[2], res[3]);

    rv[vs * 32 + b] = bestv;
    ri[vs * 32 + b] = besti;
    __syncthreads();
    if (vs == 0) {
        float bv = rv[0 * 32 + b];
        int   bi = ri[0 * 32 + b];
#pragma unroll
        for (int i = 1; i < 16; ++i) {
            const float v = rv[i * 32 + b];
            const int  ix = ri[i * 32 + b];
            if (v > bv || (v == bv && ix < bi)) { bv = v; bi = ix; }
        }
        pval[(size_t)blockIdx.x * BB + b] = bv;
        pidx[(size_t)blockIdx.x * BB + b] = bi;
    }
}

// Final argmax reduce over the 500 block partials; first-index tie-break.
__global__ void __launch_bounds__(256) argmax_final(
    const float* __restrict__ pval, const int* __restrict__ pidx,
    int nblk, int* __restrict__ tok)
{
    __shared__ float sv[256];
    __shared__ int   si[256];
    const int b   = blockIdx.x;
    const int tid = threadIdx.x;
    float bv = -3.402823e38f;
    int   bi = 0x7fffffff;
    for (int p = tid; p < nblk; p += 256) {
        const float v = pval[(size_t)p * BB + b];
        const int  ix = pidx[(size_t)p * BB + b];
        if (v > bv || (v == bv && ix < bi)) { bv = v; bi = ix; }
    }
    sv[tid] = bv; si[tid] = bi;
    __syncthreads();
    for (int s = 128; s > 0; s >>= 1) {
        if (tid < s) {
            const float v = sv[tid + s];
            const int  ix = si[tid + s];
            if (v > sv[tid] || (v == sv[tid] && ix < si[tid])) { sv[tid] = v; si[tid] = ix; }
        }
        __syncthreads();
    }
    if (tid == 0) tok[b] = si[0];
}

__global__ void __launch_bounds__(256) init_state(
    float* h0, float* c0, float* h1, float* c1, int* tok)
{
    const int i = blockIdx.x * 256 + threadIdx.x;
    if (i < BB * HID) { h0[i] = 0.f; c0[i] = 0.f; h1[i] = 0.f; c1[i] = 0.f; }
    if (i < BB) tok[i] = 1;  // BOS
}

// ---------------------------------------------------------------------------
extern "C" void kernel_launch(void* const* d_in, const int* in_sizes, int n_in,
                              void* d_out, int out_size, void* d_ws, size_t ws_size,
                              hipStream_t stream)
{
    const int*   x       = (const int*)  d_in[0];
    const float* enc_emb = (const float*)d_in[1];
    const float* dec_emb = (const float*)d_in[2];
    const float* eWih0   = (const float*)d_in[3];
    const float* eWhh0   = (const float*)d_in[4];
    const float* eb0     = (const float*)d_in[5];
    const float* eWih1   = (const float*)d_in[6];
    const float* eWhh1   = (const float*)d_in[7];
    const float* eb1     = (const float*)d_in[8];
    const float* dWih0   = (const float*)d_in[9];
    const float* dWhh0   = (const float*)d_in[10];
    const float* db0     = (const float*)d_in[11];
    const float* dWih1   = (const float*)d_in[12];
    const float* dWhh1   = (const float*)d_in[13];
    const float* db1     = (const float*)d_in[14];
    const float* pW      = (const float*)d_in[15];
    const float* pb      = (const float*)d_in[16];
    float* out = (float*)d_out;

    // workspace layout (floats): h0 ping-pong, c0, h1 ping-pong, c1, tok, argmax partials
    float* w = (float*)d_ws;
    float* h0buf[2] = { w, w + 32768 };
    float* c0       = w + 65536;
    float* h1buf[2] = { w + 98304, w + 131072 };
    float* c1       = w + 163840;
    int*   tok      = (int*)(w + 196608);
    float* pval     = w + 196608 + 64;
    int*   pidx     = (int*)(w + 196608 + 64 + 16000);

    init_state<<<dim3(128), dim3(256), 0, stream>>>(h0buf[0], c0, h1buf[0], c1, tok);

    int cur0 = 0, cur1 = 0;

    // ---- encoder: 128 steps x 2 layers ----
    for (int t = 0; t < SEQ; ++t) {
        lstm_cell<512><<<dim3(512), dim3(512), 0, stream>>>(
            nullptr, enc_emb, x, SEQ, t,
            eWih0, eWhh0, eb0, h0buf[cur0], h0buf[cur0 ^ 1], c0);
        cur0 ^= 1;
        lstm_cell<1024><<<dim3(512), dim3(512), 0, stream>>>(
            h0buf[cur0], nullptr, nullptr, 0, 0,
            eWih1, eWhh1, eb1, h1buf[cur1], h1buf[cur1 ^ 1], c1);
        cur1 ^= 1;
    }

    // ---- decoder: 64 greedy steps (state continues from encoder) ----
    for (int t = 0; t < TDEC; ++t) {
        lstm_cell<1024><<<dim3(512), dim3(512), 0, stream>>>(
            nullptr, dec_emb, tok, 1, 0,
            dWih0, dWhh0, db0, h0buf[cur0], h0buf[cur0 ^ 1], c0);
        cur0 ^= 1;
        lstm_cell<1024><<<dim3(512), dim3(512), 0, stream>>>(
            h0buf[cur0], nullptr, nullptr, 0, 0,
            dWih1, dWhh1, db1, h1buf[cur1], h1buf[cur1 ^ 1], c1);
        cur1 ^= 1;
        logits_kernel<<<dim3(500), dim3(512), 0, stream>>>(
            h1buf[cur1], pW, pb, out, t, pval, pidx);
        argmax_final<<<dim3(32), dim3(256), 0, stream>>>(pval, pidx, 500, tok);
    }
}